// Round 9
// baseline (110.692 us; speedup 1.0000x reference)
//
#include <hip/hip_runtime.h>

#define HW 16384   // H*W
#define NH 4
#define HD 16

// q/k/v workspace layout: CHANNEL-MAJOR planes  ptr[((b*NH+h)*HD + d)*HW + p]
// -> a wave's 64 consecutive-pixel lanes read CONSECUTIVE dwords (4-5 cache
// lines per load inst, vs 64 lines with pixel-major float4s). q pre-scaled.

// ---------------- Kernel 1: QKV projection (LDS-staged x, SGPR weights) ------
// grid: dim3(3, 256, 2) = (slice, strip, batch); block 256 = 64px x 4 osub
__global__ __launch_bounds__(256) void qkv_kernel(
    const float* __restrict__ x, const float* __restrict__ w,
    const float* __restrict__ bias, float* __restrict__ qT,
    float* __restrict__ kT, float* __restrict__ vT)
{
  __shared__ float xs[64][72];
  int slice = blockIdx.x;
  int p0    = blockIdx.y * 64;
  int b     = blockIdx.z;
  int t     = threadIdx.x;

  {
    int c = t >> 2, f4 = t & 3;
    const float4* src = (const float4*)(x + (size_t)(b * 64 + c) * HW + p0);
    float4* dst = (float4*)(&xs[c][0]);
#pragma unroll
    for (int k2 = 0; k2 < 4; ++k2) dst[f4 * 4 + k2] = src[f4 * 4 + k2];
  }
  __syncthreads();

  int px = t & 63;
  int wv  = __builtin_amdgcn_readfirstlane(t >> 6);
  int o16 = slice * 4 + wv;        // 0..11
  int o0  = o16 * 16;
  int tsel = o16 >> 2;             // 0=q,1=k,2=v
  int h    = o16 & 3;

  float acc[16];
#pragma unroll
  for (int d = 0; d < 16; ++d) acc[d] = bias[o0 + d];

  for (int c4 = 0; c4 < 16; ++c4) {
    float a0 = xs[c4 * 4 + 0][px];
    float a1 = xs[c4 * 4 + 1][px];
    float a2 = xs[c4 * 4 + 2][px];
    float a3 = xs[c4 * 4 + 3][px];
#pragma unroll
    for (int d = 0; d < 16; ++d) {
      const float* wr = w + (o0 + d) * 64 + c4 * 4;
      acc[d] = fmaf(wr[0], a0, acc[d]);
      acc[d] = fmaf(wr[1], a1, acc[d]);
      acc[d] = fmaf(wr[2], a2, acc[d]);
      acc[d] = fmaf(wr[3], a3, acc[d]);
    }
  }
  if (tsel == 0) {
#pragma unroll
    for (int d = 0; d < 16; ++d) acc[d] *= 0.25f;   // hd^-0.5
  }
  float* dst = (tsel == 0) ? qT : ((tsel == 1) ? kT : vT);
  // channel-major stores: 16 dword stores, 64 lanes consecutive -> 4 lines each
  float* dp = dst + ((size_t)(b * NH + h) * HD) * HW + p0 + px;
#pragma unroll
  for (int d = 0; d < 16; ++d) dp[(size_t)d * HW] = acc[d];
}

// ---------------- Kernel 2: neighborhood attention, channel-major ------------
// grid: dim3(64, 4, 2) = (256-px strip, head, batch); block 256 (4 waves).
// One thread per (pixel, head). All K/V loads are lane-dense dwords: per
// (i,d) the thread reads 7 consecutive floats (j=0..6); lane l's j-th addr
// == lane l+1's (j-1)-th -> L1 line reuse. No per-wave 64-line touches.
__global__ __launch_bounds__(256, 2) void attn_kernel(
    const float* __restrict__ qT, const float* __restrict__ kT,
    const float* __restrict__ vT, const float* __restrict__ rb,
    float* __restrict__ attO)
{
  __shared__ float rbl[169];

  int t   = threadIdx.x;
  int h   = blockIdx.y;
  int b   = blockIdx.z;
  int n   = blockIdx.x * 256 + t;
  int y   = n >> 7, xc = n & 127;
  int sy  = y - 3;  sy = sy < 0 ? 0 : (sy > 121 ? 121 : sy);
  int sx  = xc - 3; sx = sx < 0 ? 0 : (sx > 121 ? 121 : sx);
  int ih  = y - sy, iw = xc - sx;

  if (t < 169) rbl[t] = rb[t * NH + h];
  __syncthreads();

  size_t hb = (size_t)((b * NH + h) * HD) * HW;   // base of this head's planes

  float qd[16];
  {
    const float* qp = qT + hb + n;
#pragma unroll
    for (int d = 0; d < 16; ++d) qd[d] = qp[(size_t)d * HW];
  }

  // ---- init logits with bias ----
  float lg[49];
#pragma unroll
  for (int i = 0; i < 7; ++i)
#pragma unroll
    for (int j = 0; j < 7; ++j)
      lg[i * 7 + j] = rbl[(ih + i) * 13 + (iw + j)];

  // ---- pass 1: QK^T ----
  const float* kwin = kT + hb + (size_t)sy * 128 + sx;
#pragma unroll
  for (int i = 0; i < 7; ++i) {
#pragma unroll
    for (int d = 0; d < 16; ++d) {
      const float* kp = kwin + (size_t)d * HW + i * 128;
      float k0 = kp[0], k1 = kp[1], k2 = kp[2], k3 = kp[3];
      float k4 = kp[4], k5 = kp[5], k6 = kp[6];
      float q = qd[d];
      lg[i * 7 + 0] = fmaf(q, k0, lg[i * 7 + 0]);
      lg[i * 7 + 1] = fmaf(q, k1, lg[i * 7 + 1]);
      lg[i * 7 + 2] = fmaf(q, k2, lg[i * 7 + 2]);
      lg[i * 7 + 3] = fmaf(q, k3, lg[i * 7 + 3]);
      lg[i * 7 + 4] = fmaf(q, k4, lg[i * 7 + 4]);
      lg[i * 7 + 5] = fmaf(q, k5, lg[i * 7 + 5]);
      lg[i * 7 + 6] = fmaf(q, k6, lg[i * 7 + 6]);
    }
  }

  // ---- softmax ----
  float mx = lg[0];
#pragma unroll
  for (int k = 1; k < 49; ++k) mx = fmaxf(mx, lg[k]);
  float s = 0.f;
#pragma unroll
  for (int k = 0; k < 49; ++k) { lg[k] = __expf(lg[k] - mx); s += lg[k]; }
  float inv = 1.f / s;

  // ---- pass 2: PV ----
  const float* vwin = vT + hb + (size_t)sy * 128 + sx;
  float o[16];
#pragma unroll
  for (int d = 0; d < 16; ++d) o[d] = 0.f;
#pragma unroll
  for (int i = 0; i < 7; ++i) {
#pragma unroll
    for (int d = 0; d < 16; ++d) {
      const float* vp = vwin + (size_t)d * HW + i * 128;
      float v0 = vp[0], v1 = vp[1], v2 = vp[2], v3 = vp[3];
      float v4 = vp[4], v5 = vp[5], v6 = vp[6];
      float acc = o[d];
      acc = fmaf(lg[i * 7 + 0], v0, acc);
      acc = fmaf(lg[i * 7 + 1], v1, acc);
      acc = fmaf(lg[i * 7 + 2], v2, acc);
      acc = fmaf(lg[i * 7 + 3], v3, acc);
      acc = fmaf(lg[i * 7 + 4], v4, acc);
      acc = fmaf(lg[i * 7 + 5], v5, acc);
      acc = fmaf(lg[i * 7 + 6], v6, acc);
      o[d] = acc;
    }
  }

  // ---- write channel-major into attO (= d_out, overwritten by proj) ----
  float* ob = attO + (size_t)(b * 64 + h * 16) * HW + n;
#pragma unroll
  for (int d = 0; d < 16; ++d) ob[(size_t)d * HW] = o[d] * inv;
}

// ---------------- Kernel 3: output projection (in-place over d_out) ----------
__global__ __launch_bounds__(256) void proj_kernel(
    const float* __restrict__ pw, const float* __restrict__ pb,
    float* __restrict__ out)
{
  __shared__ float as[64][72];
  int p0 = blockIdx.x * 64;
  int b  = blockIdx.y;
  int t  = threadIdx.x;

  {
    int c = t >> 2, f4 = t & 3;
    const float4* src = (const float4*)(out + (size_t)(b * 64 + c) * HW + p0);
    float4* dst = (float4*)(&as[c][0]);
#pragma unroll
    for (int k2 = 0; k2 < 4; ++k2) dst[f4 * 4 + k2] = src[f4 * 4 + k2];
  }
  __syncthreads();

  int px = t & 63;
  int og = __builtin_amdgcn_readfirstlane(t >> 6);
  float acc[16];
#pragma unroll
  for (int oo = 0; oo < 16; ++oo) acc[oo] = pb[og * 16 + oo];

  for (int c4 = 0; c4 < 16; ++c4) {
    float a0 = as[c4 * 4 + 0][px];
    float a1 = as[c4 * 4 + 1][px];
    float a2 = as[c4 * 4 + 2][px];
    float a3 = as[c4 * 4 + 3][px];
#pragma unroll
    for (int oo = 0; oo < 16; ++oo) {
      const float* wr = pw + (og * 16 + oo) * 64 + c4 * 4;
      acc[oo] = fmaf(wr[0], a0, acc[oo]);
      acc[oo] = fmaf(wr[1], a1, acc[oo]);
      acc[oo] = fmaf(wr[2], a2, acc[oo]);
      acc[oo] = fmaf(wr[3], a3, acc[oo]);
    }
  }
#pragma unroll
  for (int oo = 0; oo < 16; ++oo)
    out[((size_t)b * 64 + og * 16 + oo) * HW + p0 + px] = acc[oo];
}

extern "C" void kernel_launch(void* const* d_in, const int* in_sizes, int n_in,
                              void* d_out, int out_size, void* d_ws, size_t ws_size,
                              hipStream_t stream) {
  const float* x      = (const float*)d_in[0];
  const float* qkv_w  = (const float*)d_in[1];
  const float* qkv_b  = (const float*)d_in[2];
  const float* proj_w = (const float*)d_in[3];
  const float* proj_b = (const float*)d_in[4];
  const float* rb     = (const float*)d_in[5];
  float* out = (float*)d_out;

  const size_t TSZ = (size_t)2 * NH * HW * HD;   // 2,097,152 floats each
  float* qT = (float*)d_ws;
  float* kT = qT + TSZ;
  float* vT = kT + TSZ;

  qkv_kernel<<<dim3(3, 256, 2), 256, 0, stream>>>(x, qkv_w, qkv_b, qT, kT, vT);
  attn_kernel<<<dim3(64, NH, 2), 256, 0, stream>>>(qT, kT, vT, rb, out);
  proj_kernel<<<dim3(256, 2), 256, 0, stream>>>(proj_w, proj_b, out);
}